// Round 14
// baseline (390.523 us; speedup 1.0000x reference)
//
#include <hip/hip_runtime.h>
#include <cstddef>

#define NN   30000
#define NNP  30016          /* NN ints rounded to 256B alloc granularity */
#define NE   240000
#define D1   512
#define D2   128
#define NCLS 20
#define NB   ((NN + 255) / 256)   /* 118 scan blocks */
#define CAST_TOT 1025536          /* x(960000) + 4 weights(16384 ea), float4 units */
#define IDG_TOT  (CAST_TOT + NE)  /* + one thread per edge for degree atomics */

typedef __attribute__((ext_vector_type(8))) short short8;
typedef __attribute__((ext_vector_type(4))) float f32x4;

__device__ __forceinline__ unsigned short f2b(float f) {
  union { float f; unsigned int u; } c; c.f = f;
  unsigned int r = (c.u + 0x7fff + ((c.u >> 16) & 1)) >> 16;  // RNE
  return (unsigned short)r;
}
__device__ __forceinline__ float b2f(unsigned short u) {
  union { unsigned int u; float f; } c; c.u = (unsigned int)u << 16;
  return c.f;
}

// ---------------------------------------------------------------- init+deg
__global__ __launch_bounds__(256) void k_initdeg(
    const float* __restrict__ x,
    const float* __restrict__ Wl1, const float* __restrict__ Wr1,
    const float* __restrict__ Wl2, const float* __restrict__ Wr2,
    const int* __restrict__ dst, const float* __restrict__ eattr,
    int* __restrict__ cnti, float* __restrict__ lsum,
    unsigned short* __restrict__ xb,
    unsigned short* __restrict__ Wc1, unsigned short* __restrict__ Wc2) {
  int i = blockIdx.x * 256 + threadIdx.x;
  if (i >= IDG_TOT) return;
  if (i >= CAST_TOT) {                 // degree + loop-attr atomics
    int e = i - CAST_TOT;
    int d = dst[e];
    atomicAdd(&cnti[d], 1);
    atomicAdd(&lsum[d], eattr[e]);
    return;
  }
  const float* in; unsigned short* outp; int off;
  if      (i <  960000) { in = x;   outp = xb;          off = i; }
  else if (i <  976384) { in = Wl1; outp = Wc1;         off = i -  960000; }
  else if (i <  992768) { in = Wr1; outp = Wc1 + 65536; off = i -  976384; }
  else if (i < 1009152) { in = Wl2; outp = Wc2;         off = i -  992768; }
  else                  { in = Wr2; outp = Wc2 + 65536; off = i - 1009152; }
  float4 v = ((const float4*)in)[off];
  ushort4 o;
  o.x = f2b(v.x); o.y = f2b(v.y); o.z = f2b(v.z); o.w = f2b(v.w);
  ((ushort4*)outp)[off] = o;
}

// block-scan of degrees + la; block CSR base via global atomic.
__global__ __launch_bounds__(256) void k_scan1(const int* __restrict__ cnti,
                                               const float* __restrict__ lsum,
                                               int* __restrict__ rowoff,
                                               int* __restrict__ boff,
                                               int* __restrict__ gcursor,
                                               float* __restrict__ la) {
  int i = blockIdx.x * 256 + threadIdx.x;
  int c = (i < NN) ? cnti[i] : 0;
  if (i < NN) la[i] = lsum[i] / fmaxf((float)c, 1.0f);
  int lane = threadIdx.x & 63, w = threadIdx.x >> 6;
  int v = c;
#pragma unroll
  for (int o = 1; o < 64; o <<= 1) { int t = __shfl_up(v, o); if (lane >= o) v += t; }
  __shared__ int ws[4];
  if (lane == 63) ws[w] = v;
  __syncthreads();
  int add = 0;
  for (int k = 0; k < w; k++) add += ws[k];
  v += add;
  if (i < NN) rowoff[i] = v - c;
  if (threadIdx.x == 255) boff[blockIdx.x] = atomicAdd(gcursor, v);
}

__global__ __launch_bounds__(256) void k_fill(const int* __restrict__ src,
                                              const int* __restrict__ dst,
                                              const float* __restrict__ eattr,
                                              const int* __restrict__ rowoff,
                                              const int* __restrict__ boff,
                                              int* __restrict__ cursor,
                                              int2* __restrict__ se) {
  int e = blockIdx.x * 256 + threadIdx.x;
  if (e < NE) {
    int d = dst[e];
    int pos = rowoff[d] + boff[d >> 8] + atomicAdd(&cursor[d], 1);
    se[pos] = make_int2(src[e], __float_as_int(eattr[e]));
  }
}

// ---------------------------------------------------------------- bf16 MFMA GEMM
// [Cl|Cr][m,n] = sum_k A[m,k]*W[n,k] + bias, W = [Wl;Wr] concat in n; split out.
// R7/R10 structure (both operands staged, BK=32); BN templated for occupancy.
template <int BN, int NT>   // NT = BN/32 n-tiles per wave
__global__ __launch_bounds__(256) void gemm_mfma(
    const unsigned short* __restrict__ A, const unsigned short* __restrict__ W,
    const float* __restrict__ bl, const float* __restrict__ br, int Nhalf,
    unsigned short* __restrict__ Cl, unsigned short* __restrict__ Cr,
    int M, int N, int K) {
  constexpr int BM = 128, BK = 32, LDK = BK + 8;
  __shared__ __align__(16) unsigned short As[BM * LDK];
  __shared__ __align__(16) unsigned short Bs[BN * LDK];
  const int bm = blockIdx.y * BM;
  const int bn = blockIdx.x * BN;
  const int tid = threadIdx.x;
  const int wid = tid >> 6, lane = tid & 63;
  const int wm = (wid >> 1) * 64;
  const int wn = (wid & 1) * (NT * 16);
  const int l16 = lane & 15, lq = lane >> 4;
  const int r0 = tid >> 2;
  const int ks = (tid & 3) * 8;

  f32x4 acc[4][NT];
#pragma unroll
  for (int i = 0; i < 4; ++i)
#pragma unroll
    for (int j = 0; j < NT; ++j) acc[i][j] = (f32x4){0.f, 0.f, 0.f, 0.f};

  for (int k0 = 0; k0 < K; k0 += BK) {
#pragma unroll
    for (int p = 0; p < BM / 64; ++p) {
      int r = r0 + p * 64;
      int gm = bm + r;
      uint4 v = {0u, 0u, 0u, 0u};
      if (gm < M) v = *(const uint4*)(A + (size_t)gm * K + k0 + ks);
      *(uint4*)&As[r * LDK + ks] = v;
    }
#pragma unroll
    for (int p = 0; p < BN / 64; ++p) {
      int r = r0 + p * 64;
      int gn = bn + r;
      uint4 v = {0u, 0u, 0u, 0u};
      if (gn < N) v = *(const uint4*)(W + (size_t)gn * K + k0 + ks);
      *(uint4*)&Bs[r * LDK + ks] = v;
    }
    __syncthreads();
    short8 af[4], bfr[NT];
#pragma unroll
    for (int mt = 0; mt < 4; ++mt)
      af[mt] = *(const short8*)&As[(wm + mt * 16 + l16) * LDK + lq * 8];
#pragma unroll
    for (int nt = 0; nt < NT; ++nt)
      bfr[nt] = *(const short8*)&Bs[(wn + nt * 16 + l16) * LDK + lq * 8];
#pragma unroll
    for (int mt = 0; mt < 4; ++mt)
#pragma unroll
      for (int nt = 0; nt < NT; ++nt)
        acc[mt][nt] = __builtin_amdgcn_mfma_f32_16x16x32_bf16(
            af[mt], bfr[nt], acc[mt][nt], 0, 0, 0);
    __syncthreads();
  }

#pragma unroll
  for (int mt = 0; mt < 4; ++mt)
#pragma unroll
    for (int nt = 0; nt < NT; ++nt) {
      int col = bn + wn + nt * 16 + l16;
      bool left = col < Nhalf;                 // uniform: 64-col strips
      int cc = left ? col : col - Nhalf;
      float b = left ? bl[cc] : br[cc];
      unsigned short* Cp = left ? Cl : Cr;
#pragma unroll
      for (int r = 0; r < 4; ++r) {
        int row = bm + wm + mt * 16 + lq * 4 + r;
        if (row < M) Cp[(size_t)row * Nhalf + cc] = f2b(acc[mt][nt][r] + b);
      }
    }
}

// ---------------------------------------------------------------- fused GATv2 aggregate
// R7/R10 structure (best of 6 variants): ONE wave per destination node, both
// heads (lanes [0,32)=h0, [32,64)=h1). Per-edge logit: 5-stage half-wave
// butterfly serves both heads at once. 4 edges/iteration, wgt=0 masking.
// Node-uniform state scalarized via readfirstlane.
template <int D, bool DO_SILU, bool OBF, bool HEAD_GEMM>
__global__ __launch_bounds__(256) void k_gat_node(
    const int2* __restrict__ se,
    const int* __restrict__ rowoff, const int* __restrict__ boff,
    const int* __restrict__ cnti, const float* __restrict__ la,
    const unsigned short* __restrict__ xl, const unsigned short* __restrict__ xr,
    const float* __restrict__ We, const float* __restrict__ att,
    const float* __restrict__ bias, const float* __restrict__ w_ln,
    const float* __restrict__ Wout,
    unsigned short* __restrict__ outb, float* __restrict__ outf) {
  constexpr int VEC = D / 64;      // channels per lane (8 for D1, 2 for D2)
  typedef __attribute__((ext_vector_type(VEC))) unsigned short uvec;
  const int w = __builtin_amdgcn_readfirstlane(threadIdx.x) >> 6;  // SGPR wave id
  const int n = blockIdx.x * 4 + w;                                // SGPR node
  const int lane = threadIdx.x & 63;
  const int c0 = lane * VEC;

  float xd[VEC], we[VEC], at[VEC], acc[VEC] = {};
  {
    uvec u = *(const uvec*)(xr + (size_t)n * D + c0);
#pragma unroll
    for (int k = 0; k < VEC; k++) {
      xd[k] = b2f(u[k]);
      we[k] = We[c0 + k];
      at[k] = att[c0 + k];
    }
  }

  const int start = rowoff[n] + boff[n >> 8];
  const int deg = cnti[n];
  const int total = deg + 1;                    // + self-loop
  const float lan = la[n];
  float denom = 0.f;

  for (int base = 0; base < total; base += 4) {
    int s[4]; float ea[4], wgt[4];
#pragma unroll
    for (int k = 0; k < 4; k++) {
      int idx = base + k;
      if (idx < deg) { int2 e = se[start + idx]; s[k] = e.x; ea[k] = __int_as_float(e.y); }
      else           { s[k] = n; ea[k] = lan; }
      wgt[k] = (idx < total) ? 1.f : 0.f;
    }
    uvec u[4];
#pragma unroll
    for (int k = 0; k < 4; k++)
      u[k] = *(const uvec*)(xl + (size_t)s[k] * D + c0);   // 4 gathers in flight
    float xs[4][VEC];
    float p[4] = {};
#pragma unroll
    for (int k = 0; k < VEC; k++) {
#pragma unroll
      for (int j = 0; j < 4; j++) {
        xs[j][k] = b2f(u[j][k]);
        float q = xs[j][k] + fmaf(ea[j], we[k], xd[k]);
        q = fmaxf(q, 0.2f * q);
        p[j] = fmaf(at[k], q, p[j]);
      }
    }
#pragma unroll
    for (int o = 16; o > 0; o >>= 1) {           // half-wave butterfly, 4 chains
#pragma unroll
      for (int j = 0; j < 4; j++) p[j] += __shfl_xor(p[j], o);
    }
    float pe[4];
#pragma unroll
    for (int j = 0; j < 4; j++) {
      pe[j] = __expf(p[j]) * wgt[j];
      denom += pe[j];
    }
#pragma unroll
    for (int k = 0; k < VEC; k++) {
#pragma unroll
      for (int j = 0; j < 4; j++)
        acc[k] = fmaf(pe[j], xs[j][k], acc[k]);
    }
  }

  float inv = 1.f / denom;                       // per-head (per half-wave)
  float vv[VEC], ss = 0.f;
#pragma unroll
  for (int k = 0; k < VEC; k++) {
    float v = fmaf(acc[k], inv, bias[c0 + k]);
    if (DO_SILU) v = v / (1.f + __expf(-v));
    vv[k] = v;
    ss += v * v;
  }
#pragma unroll
  for (int o = 32; o > 0; o >>= 1) ss += __shfl_xor(ss, o);   // full-wave
  float rinv = rsqrtf(ss / (float)D + 1e-5f);

  __shared__ __align__(16) float hrow[4][D2];
#pragma unroll
  for (int k = 0; k < VEC; k++) {
    float o = vv[k] * rinv * w_ln[c0 + k];
    if (OBF) outb[(size_t)n * D + c0 + k] = f2b(o);
    if (HEAD_GEMM) hrow[w][c0 + k] = o;
  }
  if (HEAD_GEMM) {
    __syncthreads();                             // no early returns: NN % 4 == 0
    int t = threadIdx.x;
    if (t < 4 * NCLS) {
      int n4 = t / NCLS, c = t % NCLS;
      const float4* wr = (const float4*)(Wout + c * D2);
      const float4* hr = (const float4*)&hrow[n4][0];
      float sm = 0.f;
#pragma unroll
      for (int q = 0; q < D2 / 4; q++) {
        float4 a = hr[q], b = wr[q];
        sm += a.x * b.x + a.y * b.y + a.z * b.z + a.w * b.w;
      }
      outf[(size_t)(blockIdx.x * 4 + n4) * NCLS + c] = sm;
    }
  }
}

// ---------------------------------------------------------------- launch
extern "C" void kernel_launch(void* const* d_in, const int* in_sizes, int n_in,
                              void* d_out, int out_size, void* d_ws, size_t ws_size,
                              hipStream_t stream) {
  const float* x     = (const float*)d_in[0];
  const int*   ei    = (const int*)  d_in[1];
  const float* eattr = (const float*)d_in[2];
  const float* Wl1   = (const float*)d_in[3];
  const float* bl1   = (const float*)d_in[4];
  const float* Wr1   = (const float*)d_in[5];
  const float* br1   = (const float*)d_in[6];
  const float* We1   = (const float*)d_in[7];
  const float* att1  = (const float*)d_in[8];
  const float* bias1 = (const float*)d_in[9];
  const float* Wl2   = (const float*)d_in[10];
  const float* bl2   = (const float*)d_in[11];
  const float* Wr2   = (const float*)d_in[12];
  const float* br2   = (const float*)d_in[13];
  const float* We2   = (const float*)d_in[14];
  const float* att2  = (const float*)d_in[15];
  const float* bias2 = (const float*)d_in[16];
  const float* w_ln1 = (const float*)d_in[17];
  const float* w_ln3 = (const float*)d_in[18];
  const float* W_out = (const float*)d_in[19];
  float* out = (float*)d_out;
  (void)in_sizes; (void)n_in; (void)out_size; (void)ws_size;

  const int* src = ei;
  const int* dst = ei + NE;

  char* wsp = (char*)d_ws;
  auto alloc = [&](size_t nbytes) {
    char* ptr = wsp;
    wsp += ((nbytes + 255) / 256) * 256;
    return ptr;
  };
  int*   cnti   = (int*)  alloc((size_t)NN * 4);   // } contiguous (NNP ints each):
  int*   cursor = (int*)  alloc((size_t)NN * 4);   // } zeroed via hipMemsetAsync;
  float* lsum   = (float*)alloc((size_t)NN * 4);   // } cursor[NN] doubles as gcursor
  float* la     = (float*)alloc((size_t)NN * 4);
  int*   rowoff = (int*)  alloc((size_t)NN * 4);
  int*   boff   = (int*)  alloc(128 * 4);
  int2*  se     = (int2*) alloc((size_t)NE * 8);
  unsigned short* xb   = (unsigned short*)alloc((size_t)NN * D2 * 2);
  unsigned short* Wc1  = (unsigned short*)alloc((size_t)2 * D1 * D2 * 2);
  unsigned short* Wc2  = (unsigned short*)alloc((size_t)2 * D2 * D1 * 2);
  unsigned short* xl1  = (unsigned short*)alloc((size_t)NN * D1 * 2);  // gather table
  unsigned short* xr1  = (unsigned short*)alloc((size_t)NN * D1 * 2);
  unsigned short* h1b  = (unsigned short*)alloc((size_t)NN * D1 * 2);
  unsigned short* xl2  = (unsigned short*)alloc((size_t)NN * D2 * 2);
  unsigned short* xr2  = (unsigned short*)alloc((size_t)NN * D2 * 2);
  int* gcursor = cursor + NN;        // inside the zeroed 3*NNP region, unused slot

  // --- preamble: memset + fused init/deg + scan(+atomic boff) + fill ---
  hipMemsetAsync(cnti, 0, (size_t)3 * NNP * 4, stream);
  k_initdeg<<<(IDG_TOT + 255) / 256, 256, 0, stream>>>(
      x, Wl1, Wr1, Wl2, Wr2, dst, eattr, cnti, lsum, xb, Wc1, Wc2);
  k_scan1<<<NB, 256, 0, stream>>>(cnti, lsum, rowoff, boff, gcursor, la);
  k_fill<<<(NE + 255) / 256, 256, 0, stream>>>(src, dst, eattr, rowoff, boff, cursor, se);

  const int GB = NN / 4;             // 4 nodes/block, 1 wave each (NN % 4 == 0)
  const int MB = (NN + 127) / 128;   // 235 row-tiles

  // --- layer 1 (MEASUREMENT ROUND: gemm launched 2x, idempotent — the
  //     total-duration delta vs R12's 324.5 µs = gemm1+gemm2 duration) ---
  gemm_mfma<128, 4><<<dim3(2 * D1 / 128, MB), 256, 0, stream>>>(
      xb, Wc1, bl1, br1, D1, xl1, xr1, NN, 2 * D1, D2);
  gemm_mfma<128, 4><<<dim3(2 * D1 / 128, MB), 256, 0, stream>>>(
      xb, Wc1, bl1, br1, D1, xl1, xr1, NN, 2 * D1, D2);
  k_gat_node<D1, true, true, false><<<GB, 256, 0, stream>>>(
      se, rowoff, boff, cnti, la, xl1, xr1, We1, att1, bias1, w_ln1, nullptr, h1b, nullptr);

  // --- layer 2 (gemm 2x as well) ---
  gemm_mfma<64, 2><<<dim3(2 * D2 / 64, MB), 256, 0, stream>>>(
      h1b, Wc2, bl2, br2, D2, xl2, xr2, NN, 2 * D2, D1);
  gemm_mfma<64, 2><<<dim3(2 * D2 / 64, MB), 256, 0, stream>>>(
      h1b, Wc2, bl2, br2, D2, xl2, xr2, NN, 2 * D2, D1);
  k_gat_node<D2, false, false, true><<<GB, 256, 0, stream>>>(
      se, rowoff, boff, cnti, la, xl2, xr2, We2, att2, bias2, w_ln3, W_out, nullptr, out);
}

// Round 15
// 316.414 us; speedup vs baseline: 1.2342x; 1.2342x over previous
//
#include <hip/hip_runtime.h>
#include <cstddef>

#define NN   30000
#define NNP  30016          /* NN ints rounded to 256B alloc granularity */
#define NE   240000
#define D1   512
#define D2   128
#define NCLS 20
#define NB   ((NN + 255) / 256)   /* 118 scan blocks */
#define CAST_TOT 1025536          /* x(960000) + 4 weights(16384 ea), float4 units */
#define IDG_TOT  (CAST_TOT + NE)  /* + one thread per edge for degree atomics */

typedef __attribute__((ext_vector_type(8))) short short8;
typedef __attribute__((ext_vector_type(4))) float f32x4;

__device__ __forceinline__ unsigned short f2b(float f) {
  union { float f; unsigned int u; } c; c.f = f;
  unsigned int r = (c.u + 0x7fff + ((c.u >> 16) & 1)) >> 16;  // RNE
  return (unsigned short)r;
}
__device__ __forceinline__ float b2f(unsigned short u) {
  union { unsigned int u; float f; } c; c.u = (unsigned int)u << 16;
  return c.f;
}

// ---------------------------------------------------------------- init+deg
__global__ __launch_bounds__(256) void k_initdeg(
    const float* __restrict__ x,
    const float* __restrict__ Wl1, const float* __restrict__ Wr1,
    const float* __restrict__ Wl2, const float* __restrict__ Wr2,
    const int* __restrict__ dst, const float* __restrict__ eattr,
    int* __restrict__ cnti, float* __restrict__ lsum,
    unsigned short* __restrict__ xb,
    unsigned short* __restrict__ Wc1, unsigned short* __restrict__ Wc2) {
  int i = blockIdx.x * 256 + threadIdx.x;
  if (i >= IDG_TOT) return;
  if (i >= CAST_TOT) {                 // degree + loop-attr atomics
    int e = i - CAST_TOT;
    int d = dst[e];
    atomicAdd(&cnti[d], 1);
    atomicAdd(&lsum[d], eattr[e]);
    return;
  }
  const float* in; unsigned short* outp; int off;
  if      (i <  960000) { in = x;   outp = xb;          off = i; }
  else if (i <  976384) { in = Wl1; outp = Wc1;         off = i -  960000; }
  else if (i <  992768) { in = Wr1; outp = Wc1 + 65536; off = i -  976384; }
  else if (i < 1009152) { in = Wl2; outp = Wc2;         off = i -  992768; }
  else                  { in = Wr2; outp = Wc2 + 65536; off = i - 1009152; }
  float4 v = ((const float4*)in)[off];
  ushort4 o;
  o.x = f2b(v.x); o.y = f2b(v.y); o.z = f2b(v.z); o.w = f2b(v.w);
  ((ushort4*)outp)[off] = o;
}

// block-scan of degrees + la; block CSR base via global atomic.
__global__ __launch_bounds__(256) void k_scan1(const int* __restrict__ cnti,
                                               const float* __restrict__ lsum,
                                               int* __restrict__ rowoff,
                                               int* __restrict__ boff,
                                               int* __restrict__ gcursor,
                                               float* __restrict__ la) {
  int i = blockIdx.x * 256 + threadIdx.x;
  int c = (i < NN) ? cnti[i] : 0;
  if (i < NN) la[i] = lsum[i] / fmaxf((float)c, 1.0f);
  int lane = threadIdx.x & 63, w = threadIdx.x >> 6;
  int v = c;
#pragma unroll
  for (int o = 1; o < 64; o <<= 1) { int t = __shfl_up(v, o); if (lane >= o) v += t; }
  __shared__ int ws[4];
  if (lane == 63) ws[w] = v;
  __syncthreads();
  int add = 0;
  for (int k = 0; k < w; k++) add += ws[k];
  v += add;
  if (i < NN) rowoff[i] = v - c;
  if (threadIdx.x == 255) boff[blockIdx.x] = atomicAdd(gcursor, v);
}

__global__ __launch_bounds__(256) void k_fill(const int* __restrict__ src,
                                              const int* __restrict__ dst,
                                              const float* __restrict__ eattr,
                                              const int* __restrict__ rowoff,
                                              const int* __restrict__ boff,
                                              int* __restrict__ cursor,
                                              int2* __restrict__ se) {
  int e = blockIdx.x * 256 + threadIdx.x;
  if (e < NE) {
    int d = dst[e];
    int pos = rowoff[d] + boff[d >> 8] + atomicAdd(&cursor[d], 1);
    se[pos] = make_int2(src[e], __float_as_int(eattr[e]));
  }
}

// ---------------------------------------------------------------- bf16 MFMA GEMM
// [Cl|Cr][m,n] = sum_k A[m,k]*W[n,k] + bias, W = [Wl;Wr] concat in n; split out.
// m97-style staging: BK=64, UNPADDED LDS, global_load_lds width=16 — lane l of
// wave w lands at LDS byte w*1024 + l*16 (wave-uniform base + lane*16; the
// mapping row=lane>>3, kchunk=lane&7 makes that exactly lane-contiguous).
// No OOB row guard: reads past M land in later workspace buffers (no fault);
// garbage only contaminates rows >= M, which the epilogue store masks.
template <int BN, int NT>   // NT = BN/32 n-tiles per wave
__global__ __launch_bounds__(256) void gemm_mfma(
    const unsigned short* __restrict__ A, const unsigned short* __restrict__ W,
    const float* __restrict__ bl, const float* __restrict__ br, int Nhalf,
    unsigned short* __restrict__ Cl, unsigned short* __restrict__ Cr,
    int M, int N, int K) {
  constexpr int BM = 128, BK = 64, LDK = BK;   // unpadded (global_load_lds)
  __shared__ __align__(16) unsigned short As[BM * LDK];
  __shared__ __align__(16) unsigned short Bs[BN * LDK];
  const int bm = blockIdx.y * BM;
  const int bn = blockIdx.x * BN;
  const int tid = threadIdx.x;
  const int lane = tid & 63;
  const int wid = __builtin_amdgcn_readfirstlane(tid >> 6);  // wave-uniform (SGPR)
  const int wm = (wid >> 1) * 64;
  const int wn = (wid & 1) * (NT * 16);
  const int l16 = lane & 15, lq = lane >> 4;
  const int lrow = lane >> 3;          // staging: row-in-8
  const int lcol = (lane & 7) * 8;     // staging: k-offset (8 bf16 = 16 B)

  f32x4 acc[4][NT];
#pragma unroll
  for (int i = 0; i < 4; ++i)
#pragma unroll
    for (int j = 0; j < NT; ++j) acc[i][j] = (f32x4){0.f, 0.f, 0.f, 0.f};

  for (int k0 = 0; k0 < K; k0 += BK) {
    // A tile: BM/32 passes; each wave stages 8 rows x 64k per pass.
#pragma unroll
    for (int p = 0; p < BM / 32; ++p) {
      int r = p * 32 + wid * 8;
      const unsigned short* gp = A + (size_t)(bm + r + lrow) * K + k0 + lcol;
      __builtin_amdgcn_global_load_lds(
          (const __attribute__((address_space(1))) unsigned int*)gp,
          (__attribute__((address_space(3))) unsigned int*)(As + (size_t)r * LDK),
          16, 0, 0);
    }
#pragma unroll
    for (int p = 0; p < BN / 32; ++p) {
      int r = p * 32 + wid * 8;
      const unsigned short* gp = W + (size_t)(bn + r + lrow) * K + k0 + lcol;
      __builtin_amdgcn_global_load_lds(
          (const __attribute__((address_space(1))) unsigned int*)gp,
          (__attribute__((address_space(3))) unsigned int*)(Bs + (size_t)r * LDK),
          16, 0, 0);
    }
    __syncthreads();
#pragma unroll
    for (int kh = 0; kh < 2; ++kh) {
      short8 af[4], bfr[NT];
#pragma unroll
      for (int mt = 0; mt < 4; ++mt)
        af[mt] = *(const short8*)&As[(wm + mt * 16 + l16) * LDK + kh * 32 + lq * 8];
#pragma unroll
      for (int nt = 0; nt < NT; ++nt)
        bfr[nt] = *(const short8*)&Bs[(wn + nt * 16 + l16) * LDK + kh * 32 + lq * 8];
#pragma unroll
      for (int mt = 0; mt < 4; ++mt)
#pragma unroll
        for (int nt = 0; nt < NT; ++nt)
          acc[mt][nt] = __builtin_amdgcn_mfma_f32_16x16x32_bf16(
              af[mt], bfr[nt], acc[mt][nt], 0, 0, 0);
    }
    __syncthreads();
  }

#pragma unroll
  for (int mt = 0; mt < 4; ++mt)
#pragma unroll
    for (int nt = 0; nt < NT; ++nt) {
      int col = bn + wn + nt * 16 + l16;
      bool left = col < Nhalf;                 // uniform: 64-col strips
      int cc = left ? col : col - Nhalf;
      float b = left ? bl[cc] : br[cc];
      unsigned short* Cp = left ? Cl : Cr;
#pragma unroll
      for (int r = 0; r < 4; ++r) {
        int row = bm + wm + mt * 16 + lq * 4 + r;
        if (row < M) Cp[(size_t)row * Nhalf + cc] = f2b(acc[mt][nt][r] + b);
      }
    }
}

// ---------------------------------------------------------------- fused GATv2 aggregate
// R7/R10 structure (best of 6 variants): ONE wave per destination node, both
// heads (lanes [0,32)=h0, [32,64)=h1). Per-edge logit: 5-stage half-wave
// butterfly serves both heads at once. 4 edges/iteration, wgt=0 masking.
// Node-uniform state scalarized via readfirstlane.
template <int D, bool DO_SILU, bool OBF, bool HEAD_GEMM>
__global__ __launch_bounds__(256) void k_gat_node(
    const int2* __restrict__ se,
    const int* __restrict__ rowoff, const int* __restrict__ boff,
    const int* __restrict__ cnti, const float* __restrict__ la,
    const unsigned short* __restrict__ xl, const unsigned short* __restrict__ xr,
    const float* __restrict__ We, const float* __restrict__ att,
    const float* __restrict__ bias, const float* __restrict__ w_ln,
    const float* __restrict__ Wout,
    unsigned short* __restrict__ outb, float* __restrict__ outf) {
  constexpr int VEC = D / 64;      // channels per lane (8 for D1, 2 for D2)
  typedef __attribute__((ext_vector_type(VEC))) unsigned short uvec;
  const int w = __builtin_amdgcn_readfirstlane(threadIdx.x) >> 6;  // SGPR wave id
  const int n = blockIdx.x * 4 + w;                                // SGPR node
  const int lane = threadIdx.x & 63;
  const int c0 = lane * VEC;

  float xd[VEC], we[VEC], at[VEC], acc[VEC] = {};
  {
    uvec u = *(const uvec*)(xr + (size_t)n * D + c0);
#pragma unroll
    for (int k = 0; k < VEC; k++) {
      xd[k] = b2f(u[k]);
      we[k] = We[c0 + k];
      at[k] = att[c0 + k];
    }
  }

  const int start = rowoff[n] + boff[n >> 8];
  const int deg = cnti[n];
  const int total = deg + 1;                    // + self-loop
  const float lan = la[n];
  float denom = 0.f;

  for (int base = 0; base < total; base += 4) {
    int s[4]; float ea[4], wgt[4];
#pragma unroll
    for (int k = 0; k < 4; k++) {
      int idx = base + k;
      if (idx < deg) { int2 e = se[start + idx]; s[k] = e.x; ea[k] = __int_as_float(e.y); }
      else           { s[k] = n; ea[k] = lan; }
      wgt[k] = (idx < total) ? 1.f : 0.f;
    }
    uvec u[4];
#pragma unroll
    for (int k = 0; k < 4; k++)
      u[k] = *(const uvec*)(xl + (size_t)s[k] * D + c0);   // 4 gathers in flight
    float xs[4][VEC];
    float p[4] = {};
#pragma unroll
    for (int k = 0; k < VEC; k++) {
#pragma unroll
      for (int j = 0; j < 4; j++) {
        xs[j][k] = b2f(u[j][k]);
        float q = xs[j][k] + fmaf(ea[j], we[k], xd[k]);
        q = fmaxf(q, 0.2f * q);
        p[j] = fmaf(at[k], q, p[j]);
      }
    }
#pragma unroll
    for (int o = 16; o > 0; o >>= 1) {           // half-wave butterfly, 4 chains
#pragma unroll
      for (int j = 0; j < 4; j++) p[j] += __shfl_xor(p[j], o);
    }
    float pe[4];
#pragma unroll
    for (int j = 0; j < 4; j++) {
      pe[j] = __expf(p[j]) * wgt[j];
      denom += pe[j];
    }
#pragma unroll
    for (int k = 0; k < VEC; k++) {
#pragma unroll
      for (int j = 0; j < 4; j++)
        acc[k] = fmaf(pe[j], xs[j][k], acc[k]);
    }
  }

  float inv = 1.f / denom;                       // per-head (per half-wave)
  float vv[VEC], ss = 0.f;
#pragma unroll
  for (int k = 0; k < VEC; k++) {
    float v = fmaf(acc[k], inv, bias[c0 + k]);
    if (DO_SILU) v = v / (1.f + __expf(-v));
    vv[k] = v;
    ss += v * v;
  }
#pragma unroll
  for (int o = 32; o > 0; o >>= 1) ss += __shfl_xor(ss, o);   // full-wave
  float rinv = rsqrtf(ss / (float)D + 1e-5f);

  __shared__ __align__(16) float hrow[4][D2];
#pragma unroll
  for (int k = 0; k < VEC; k++) {
    float o = vv[k] * rinv * w_ln[c0 + k];
    if (OBF) outb[(size_t)n * D + c0 + k] = f2b(o);
    if (HEAD_GEMM) hrow[w][c0 + k] = o;
  }
  if (HEAD_GEMM) {
    __syncthreads();                             // no early returns: NN % 4 == 0
    int t = threadIdx.x;
    if (t < 4 * NCLS) {
      int n4 = t / NCLS, c = t % NCLS;
      const float4* wr = (const float4*)(Wout + c * D2);
      const float4* hr = (const float4*)&hrow[n4][0];
      float sm = 0.f;
#pragma unroll
      for (int q = 0; q < D2 / 4; q++) {
        float4 a = hr[q], b = wr[q];
        sm += a.x * b.x + a.y * b.y + a.z * b.z + a.w * b.w;
      }
      outf[(size_t)(blockIdx.x * 4 + n4) * NCLS + c] = sm;
    }
  }
}

// ---------------------------------------------------------------- launch
extern "C" void kernel_launch(void* const* d_in, const int* in_sizes, int n_in,
                              void* d_out, int out_size, void* d_ws, size_t ws_size,
                              hipStream_t stream) {
  const float* x     = (const float*)d_in[0];
  const int*   ei    = (const int*)  d_in[1];
  const float* eattr = (const float*)d_in[2];
  const float* Wl1   = (const float*)d_in[3];
  const float* bl1   = (const float*)d_in[4];
  const float* Wr1   = (const float*)d_in[5];
  const float* br1   = (const float*)d_in[6];
  const float* We1   = (const float*)d_in[7];
  const float* att1  = (const float*)d_in[8];
  const float* bias1 = (const float*)d_in[9];
  const float* Wl2   = (const float*)d_in[10];
  const float* bl2   = (const float*)d_in[11];
  const float* Wr2   = (const float*)d_in[12];
  const float* br2   = (const float*)d_in[13];
  const float* We2   = (const float*)d_in[14];
  const float* att2  = (const float*)d_in[15];
  const float* bias2 = (const float*)d_in[16];
  const float* w_ln1 = (const float*)d_in[17];
  const float* w_ln3 = (const float*)d_in[18];
  const float* W_out = (const float*)d_in[19];
  float* out = (float*)d_out;
  (void)in_sizes; (void)n_in; (void)out_size; (void)ws_size;

  const int* src = ei;
  const int* dst = ei + NE;

  char* wsp = (char*)d_ws;
  auto alloc = [&](size_t nbytes) {
    char* ptr = wsp;
    wsp += ((nbytes + 255) / 256) * 256;
    return ptr;
  };
  int*   cnti   = (int*)  alloc((size_t)NN * 4);   // } contiguous (NNP ints each):
  int*   cursor = (int*)  alloc((size_t)NN * 4);   // } zeroed via hipMemsetAsync;
  float* lsum   = (float*)alloc((size_t)NN * 4);   // } cursor[NN] doubles as gcursor
  float* la     = (float*)alloc((size_t)NN * 4);
  int*   rowoff = (int*)  alloc((size_t)NN * 4);
  int*   boff   = (int*)  alloc(128 * 4);
  int2*  se     = (int2*) alloc((size_t)NE * 8);
  unsigned short* xb   = (unsigned short*)alloc((size_t)NN * D2 * 2);
  unsigned short* Wc1  = (unsigned short*)alloc((size_t)2 * D1 * D2 * 2);
  unsigned short* Wc2  = (unsigned short*)alloc((size_t)2 * D2 * D1 * 2);
  unsigned short* xl1  = (unsigned short*)alloc((size_t)NN * D1 * 2);  // gather table
  unsigned short* xr1  = (unsigned short*)alloc((size_t)NN * D1 * 2);
  unsigned short* h1b  = (unsigned short*)alloc((size_t)NN * D1 * 2);
  unsigned short* xl2  = (unsigned short*)alloc((size_t)NN * D2 * 2);
  unsigned short* xr2  = (unsigned short*)alloc((size_t)NN * D2 * 2);
  int* gcursor = cursor + NN;        // inside the zeroed 3*NNP region, unused slot

  // --- preamble: memset + fused init/deg + scan(+atomic boff) + fill ---
  hipMemsetAsync(cnti, 0, (size_t)3 * NNP * 4, stream);
  k_initdeg<<<(IDG_TOT + 255) / 256, 256, 0, stream>>>(
      x, Wl1, Wr1, Wl2, Wr2, dst, eattr, cnti, lsum, xb, Wc1, Wc2);
  k_scan1<<<NB, 256, 0, stream>>>(cnti, lsum, rowoff, boff, gcursor, la);
  k_fill<<<(NE + 255) / 256, 256, 0, stream>>>(src, dst, eattr, rowoff, boff, cursor, se);

  const int GB = NN / 4;             // 4 nodes/block, 1 wave each (NN % 4 == 0)
  const int MB = (NN + 127) / 128;   // 235 row-tiles

  // --- layer 1: [xl1|xr1] = x @ [Wl1;Wr1]^T + [bl1;br1]  (split bf16 out) ---
  gemm_mfma<128, 4><<<dim3(2 * D1 / 128, MB), 256, 0, stream>>>(
      xb, Wc1, bl1, br1, D1, xl1, xr1, NN, 2 * D1, D2);
  k_gat_node<D1, true, true, false><<<GB, 256, 0, stream>>>(
      se, rowoff, boff, cnti, la, xl1, xr1, We1, att1, bias1, w_ln1, nullptr, h1b, nullptr);

  // --- layer 2: [xl2|xr2] = h1 @ [Wl2;Wr2]^T + [bl2;br2]  (split bf16 out) ---
  gemm_mfma<64, 2><<<dim3(2 * D2 / 64, MB), 256, 0, stream>>>(
      h1b, Wc2, bl2, br2, D2, xl2, xr2, NN, 2 * D2, D1);
  k_gat_node<D2, false, false, true><<<GB, 256, 0, stream>>>(
      se, rowoff, boff, cnti, la, xl2, xr2, We2, att2, bias2, w_ln3, W_out, nullptr, out);
}

// Round 17
// 312.513 us; speedup vs baseline: 1.2496x; 1.0125x over previous
//
#include <hip/hip_runtime.h>
#include <cstddef>

#define NN   30000
#define NNP  30016          /* NN ints rounded to 256B alloc granularity */
#define NE   240000
#define D1   512
#define D2   128
#define NCLS 20
#define NB   ((NN + 255) / 256)   /* 118 scan blocks */
#define CAST_TOT 1025536          /* x(960000) + 4 weights(16384 ea), float4 units */
#define IDG_TOT  (CAST_TOT + NE)  /* + one thread per edge for degree atomics */

typedef __attribute__((ext_vector_type(8))) short short8;
typedef __attribute__((ext_vector_type(4))) float f32x4;

__device__ __forceinline__ unsigned short f2b(float f) {
  union { float f; unsigned int u; } c; c.f = f;
  unsigned int r = (c.u + 0x7fff + ((c.u >> 16) & 1)) >> 16;  // RNE
  return (unsigned short)r;
}
__device__ __forceinline__ float b2f(unsigned short u) {
  union { unsigned int u; float f; } c; c.u = (unsigned int)u << 16;
  return c.f;
}

// ---------------------------------------------------------------- init+deg
__global__ __launch_bounds__(256) void k_initdeg(
    const float* __restrict__ x,
    const float* __restrict__ Wl1, const float* __restrict__ Wr1,
    const float* __restrict__ Wl2, const float* __restrict__ Wr2,
    const int* __restrict__ dst, const float* __restrict__ eattr,
    int* __restrict__ cnti, float* __restrict__ lsum,
    unsigned short* __restrict__ xb,
    unsigned short* __restrict__ Wc1, unsigned short* __restrict__ Wc2) {
  int i = blockIdx.x * 256 + threadIdx.x;
  if (i >= IDG_TOT) return;
  if (i >= CAST_TOT) {                 // degree + loop-attr atomics
    int e = i - CAST_TOT;
    int d = dst[e];
    atomicAdd(&cnti[d], 1);
    atomicAdd(&lsum[d], eattr[e]);
    return;
  }
  const float* in; unsigned short* outp; int off;
  if      (i <  960000) { in = x;   outp = xb;          off = i; }
  else if (i <  976384) { in = Wl1; outp = Wc1;         off = i -  960000; }
  else if (i <  992768) { in = Wr1; outp = Wc1 + 65536; off = i -  976384; }
  else if (i < 1009152) { in = Wl2; outp = Wc2;         off = i -  992768; }
  else                  { in = Wr2; outp = Wc2 + 65536; off = i - 1009152; }
  float4 v = ((const float4*)in)[off];
  ushort4 o;
  o.x = f2b(v.x); o.y = f2b(v.y); o.z = f2b(v.z); o.w = f2b(v.w);
  ((ushort4*)outp)[off] = o;
}

// block-scan of degrees + la; block CSR base via global atomic.
__global__ __launch_bounds__(256) void k_scan1(const int* __restrict__ cnti,
                                               const float* __restrict__ lsum,
                                               int* __restrict__ rowoff,
                                               int* __restrict__ boff,
                                               int* __restrict__ gcursor,
                                               float* __restrict__ la) {
  int i = blockIdx.x * 256 + threadIdx.x;
  int c = (i < NN) ? cnti[i] : 0;
  if (i < NN) la[i] = lsum[i] / fmaxf((float)c, 1.0f);
  int lane = threadIdx.x & 63, w = threadIdx.x >> 6;
  int v = c;
#pragma unroll
  for (int o = 1; o < 64; o <<= 1) { int t = __shfl_up(v, o); if (lane >= o) v += t; }
  __shared__ int ws[4];
  if (lane == 63) ws[w] = v;
  __syncthreads();
  int add = 0;
  for (int k = 0; k < w; k++) add += ws[k];
  v += add;
  if (i < NN) rowoff[i] = v - c;
  if (threadIdx.x == 255) boff[blockIdx.x] = atomicAdd(gcursor, v);
}

__global__ __launch_bounds__(256) void k_fill(const int* __restrict__ src,
                                              const int* __restrict__ dst,
                                              const float* __restrict__ eattr,
                                              const int* __restrict__ rowoff,
                                              const int* __restrict__ boff,
                                              int* __restrict__ cursor,
                                              int2* __restrict__ se) {
  int e = blockIdx.x * 256 + threadIdx.x;
  if (e < NE) {
    int d = dst[e];
    int pos = rowoff[d] + boff[d >> 8] + atomicAdd(&cursor[d], 1);
    se[pos] = make_int2(src[e], __float_as_int(eattr[e]));
  }
}

// ---------------------------------------------------------------- bf16 MFMA GEMM
// [Cl|Cr][m,n] = sum_k A[m,k]*W[n,k] + bias, W = [Wl;Wr] concat in n; split out.
// m97-style staging: BK=64, UNPADDED LDS, global_load_lds width=16 — lane l of
// wave w lands at LDS byte w*1024 + l*16 (wave-uniform base + lane*16; the
// mapping row=lane>>3, kchunk=lane&7 makes that exactly lane-contiguous).
// No OOB row guard: reads past M land in later workspace buffers (no fault);
// garbage only contaminates rows >= M, which the epilogue store masks.
template <int BN, int NT>   // NT = BN/32 n-tiles per wave
__global__ __launch_bounds__(256) void gemm_mfma(
    const unsigned short* __restrict__ A, const unsigned short* __restrict__ W,
    const float* __restrict__ bl, const float* __restrict__ br, int Nhalf,
    unsigned short* __restrict__ Cl, unsigned short* __restrict__ Cr,
    int M, int N, int K) {
  constexpr int BM = 128, BK = 64, LDK = BK;   // unpadded (global_load_lds)
  __shared__ __align__(16) unsigned short As[BM * LDK];
  __shared__ __align__(16) unsigned short Bs[BN * LDK];
  const int bm = blockIdx.y * BM;
  const int bn = blockIdx.x * BN;
  const int tid = threadIdx.x;
  const int lane = tid & 63;
  const int wid = __builtin_amdgcn_readfirstlane(tid >> 6);  // wave-uniform (SGPR)
  const int wm = (wid >> 1) * 64;
  const int wn = (wid & 1) * (NT * 16);
  const int l16 = lane & 15, lq = lane >> 4;
  const int lrow = lane >> 3;          // staging: row-in-8
  const int lcol = (lane & 7) * 8;     // staging: k-offset (8 bf16 = 16 B)

  f32x4 acc[4][NT];
#pragma unroll
  for (int i = 0; i < 4; ++i)
#pragma unroll
    for (int j = 0; j < NT; ++j) acc[i][j] = (f32x4){0.f, 0.f, 0.f, 0.f};

  for (int k0 = 0; k0 < K; k0 += BK) {
    // A tile: BM/32 passes; each wave stages 8 rows x 64k per pass.
#pragma unroll
    for (int p = 0; p < BM / 32; ++p) {
      int r = p * 32 + wid * 8;
      const unsigned short* gp = A + (size_t)(bm + r + lrow) * K + k0 + lcol;
      __builtin_amdgcn_global_load_lds(
          (const __attribute__((address_space(1))) unsigned int*)gp,
          (__attribute__((address_space(3))) unsigned int*)(As + (size_t)r * LDK),
          16, 0, 0);
    }
#pragma unroll
    for (int p = 0; p < BN / 32; ++p) {
      int r = p * 32 + wid * 8;
      const unsigned short* gp = W + (size_t)(bn + r + lrow) * K + k0 + lcol;
      __builtin_amdgcn_global_load_lds(
          (const __attribute__((address_space(1))) unsigned int*)gp,
          (__attribute__((address_space(3))) unsigned int*)(Bs + (size_t)r * LDK),
          16, 0, 0);
    }
    __syncthreads();
#pragma unroll
    for (int kh = 0; kh < 2; ++kh) {
      short8 af[4], bfr[NT];
#pragma unroll
      for (int mt = 0; mt < 4; ++mt)
        af[mt] = *(const short8*)&As[(wm + mt * 16 + l16) * LDK + kh * 32 + lq * 8];
#pragma unroll
      for (int nt = 0; nt < NT; ++nt)
        bfr[nt] = *(const short8*)&Bs[(wn + nt * 16 + l16) * LDK + kh * 32 + lq * 8];
#pragma unroll
      for (int mt = 0; mt < 4; ++mt)
#pragma unroll
        for (int nt = 0; nt < NT; ++nt)
          acc[mt][nt] = __builtin_amdgcn_mfma_f32_16x16x32_bf16(
              af[mt], bfr[nt], acc[mt][nt], 0, 0, 0);
    }
    __syncthreads();
  }

#pragma unroll
  for (int mt = 0; mt < 4; ++mt)
#pragma unroll
    for (int nt = 0; nt < NT; ++nt) {
      int col = bn + wn + nt * 16 + l16;
      bool left = col < Nhalf;                 // uniform: 64-col strips
      int cc = left ? col : col - Nhalf;
      float b = left ? bl[cc] : br[cc];
      unsigned short* Cp = left ? Cl : Cr;
#pragma unroll
      for (int r = 0; r < 4; ++r) {
        int row = bm + wm + mt * 16 + lq * 4 + r;
        if (row < M) Cp[(size_t)row * Nhalf + cc] = f2b(acc[mt][nt][r] + b);
      }
    }
}

// ---------------------------------------------------------------- fused GATv2 aggregate
// R7/R10 structure (best of 6 variants): ONE wave per destination node, both
// heads (lanes [0,32)=h0, [32,64)=h1). Per-edge logit: 5-stage half-wave
// butterfly serves both heads at once. 4 edges/iteration, wgt=0 masking.
// Node-uniform state scalarized via readfirstlane.
template <int D, bool DO_SILU, bool OBF, bool HEAD_GEMM>
__global__ __launch_bounds__(256) void k_gat_node(
    const int2* __restrict__ se,
    const int* __restrict__ rowoff, const int* __restrict__ boff,
    const int* __restrict__ cnti, const float* __restrict__ la,
    const unsigned short* __restrict__ xl, const unsigned short* __restrict__ xr,
    const float* __restrict__ We, const float* __restrict__ att,
    const float* __restrict__ bias, const float* __restrict__ w_ln,
    const float* __restrict__ Wout,
    unsigned short* __restrict__ outb, float* __restrict__ outf) {
  constexpr int VEC = D / 64;      // channels per lane (8 for D1, 2 for D2)
  typedef __attribute__((ext_vector_type(VEC))) unsigned short uvec;
  const int w = __builtin_amdgcn_readfirstlane(threadIdx.x) >> 6;  // SGPR wave id
  const int n = blockIdx.x * 4 + w;                                // SGPR node
  const int lane = threadIdx.x & 63;
  const int c0 = lane * VEC;

  float xd[VEC], we[VEC], at[VEC], acc[VEC] = {};
  {
    uvec u = *(const uvec*)(xr + (size_t)n * D + c0);
#pragma unroll
    for (int k = 0; k < VEC; k++) {
      xd[k] = b2f(u[k]);
      we[k] = We[c0 + k];
      at[k] = att[c0 + k];
    }
  }

  const int start = rowoff[n] + boff[n >> 8];
  const int deg = cnti[n];
  const int total = deg + 1;                    // + self-loop
  const float lan = la[n];
  float denom = 0.f;

  for (int base = 0; base < total; base += 4) {
    int s[4]; float ea[4], wgt[4];
#pragma unroll
    for (int k = 0; k < 4; k++) {
      int idx = base + k;
      if (idx < deg) { int2 e = se[start + idx]; s[k] = e.x; ea[k] = __int_as_float(e.y); }
      else           { s[k] = n; ea[k] = lan; }
      wgt[k] = (idx < total) ? 1.f : 0.f;
    }
    uvec u[4];
#pragma unroll
    for (int k = 0; k < 4; k++)
      u[k] = *(const uvec*)(xl + (size_t)s[k] * D + c0);   // 4 gathers in flight
    float xs[4][VEC];
    float p[4] = {};
#pragma unroll
    for (int k = 0; k < VEC; k++) {
#pragma unroll
      for (int j = 0; j < 4; j++) {
        xs[j][k] = b2f(u[j][k]);
        float q = xs[j][k] + fmaf(ea[j], we[k], xd[k]);
        q = fmaxf(q, 0.2f * q);
        p[j] = fmaf(at[k], q, p[j]);
      }
    }
#pragma unroll
    for (int o = 16; o > 0; o >>= 1) {           // half-wave butterfly, 4 chains
#pragma unroll
      for (int j = 0; j < 4; j++) p[j] += __shfl_xor(p[j], o);
    }
    float pe[4];
#pragma unroll
    for (int j = 0; j < 4; j++) {
      pe[j] = __expf(p[j]) * wgt[j];
      denom += pe[j];
    }
#pragma unroll
    for (int k = 0; k < VEC; k++) {
#pragma unroll
      for (int j = 0; j < 4; j++)
        acc[k] = fmaf(pe[j], xs[j][k], acc[k]);
    }
  }

  float inv = 1.f / denom;                       // per-head (per half-wave)
  float vv[VEC], ss = 0.f;
#pragma unroll
  for (int k = 0; k < VEC; k++) {
    float v = fmaf(acc[k], inv, bias[c0 + k]);
    if (DO_SILU) v = v / (1.f + __expf(-v));
    vv[k] = v;
    ss += v * v;
  }
#pragma unroll
  for (int o = 32; o > 0; o >>= 1) ss += __shfl_xor(ss, o);   // full-wave
  float rinv = rsqrtf(ss / (float)D + 1e-5f);

  __shared__ __align__(16) float hrow[4][D2];
#pragma unroll
  for (int k = 0; k < VEC; k++) {
    float o = vv[k] * rinv * w_ln[c0 + k];
    if (OBF) outb[(size_t)n * D + c0 + k] = f2b(o);
    if (HEAD_GEMM) hrow[w][c0 + k] = o;
  }
  if (HEAD_GEMM) {
    __syncthreads();                             // no early returns: NN % 4 == 0
    int t = threadIdx.x;
    if (t < 4 * NCLS) {
      int n4 = t / NCLS, c = t % NCLS;
      const float4* wr = (const float4*)(Wout + c * D2);
      const float4* hr = (const float4*)&hrow[n4][0];
      float sm = 0.f;
#pragma unroll
      for (int q = 0; q < D2 / 4; q++) {
        float4 a = hr[q], b = wr[q];
        sm += a.x * b.x + a.y * b.y + a.z * b.z + a.w * b.w;
      }
      outf[(size_t)(blockIdx.x * 4 + n4) * NCLS + c] = sm;
    }
  }
}

// ---------------------------------------------------------------- launch
extern "C" void kernel_launch(void* const* d_in, const int* in_sizes, int n_in,
                              void* d_out, int out_size, void* d_ws, size_t ws_size,
                              hipStream_t stream) {
  const float* x     = (const float*)d_in[0];
  const int*   ei    = (const int*)  d_in[1];
  const float* eattr = (const float*)d_in[2];
  const float* Wl1   = (const float*)d_in[3];
  const float* bl1   = (const float*)d_in[4];
  const float* Wr1   = (const float*)d_in[5];
  const float* br1   = (const float*)d_in[6];
  const float* We1   = (const float*)d_in[7];
  const float* att1  = (const float*)d_in[8];
  const float* bias1 = (const float*)d_in[9];
  const float* Wl2   = (const float*)d_in[10];
  const float* bl2   = (const float*)d_in[11];
  const float* Wr2   = (const float*)d_in[12];
  const float* br2   = (const float*)d_in[13];
  const float* We2   = (const float*)d_in[14];
  const float* att2  = (const float*)d_in[15];
  const float* bias2 = (const float*)d_in[16];
  const float* w_ln1 = (const float*)d_in[17];
  const float* w_ln3 = (const float*)d_in[18];
  const float* W_out = (const float*)d_in[19];
  float* out = (float*)d_out;
  (void)in_sizes; (void)n_in; (void)out_size; (void)ws_size;

  const int* src = ei;
  const int* dst = ei + NE;

  char* wsp = (char*)d_ws;
  auto alloc = [&](size_t nbytes) {
    char* ptr = wsp;
    wsp += ((nbytes + 255) / 256) * 256;
    return ptr;
  };
  int*   cnti   = (int*)  alloc((size_t)NN * 4);   // } contiguous (NNP ints each):
  int*   cursor = (int*)  alloc((size_t)NN * 4);   // } zeroed via hipMemsetAsync;
  float* lsum   = (float*)alloc((size_t)NN * 4);   // } cursor[NN] doubles as gcursor
  float* la     = (float*)alloc((size_t)NN * 4);
  int*   rowoff = (int*)  alloc((size_t)NN * 4);
  int*   boff   = (int*)  alloc(128 * 4);
  int2*  se     = (int2*) alloc((size_t)NE * 8);
  unsigned short* xb   = (unsigned short*)alloc((size_t)NN * D2 * 2);
  unsigned short* Wc1  = (unsigned short*)alloc((size_t)2 * D1 * D2 * 2);
  unsigned short* Wc2  = (unsigned short*)alloc((size_t)2 * D2 * D1 * 2);
  unsigned short* xl1  = (unsigned short*)alloc((size_t)NN * D1 * 2);  // gather table
  unsigned short* xr1  = (unsigned short*)alloc((size_t)NN * D1 * 2);
  unsigned short* h1b  = (unsigned short*)alloc((size_t)NN * D1 * 2);
  unsigned short* xl2  = (unsigned short*)alloc((size_t)NN * D2 * 2);
  unsigned short* xr2  = (unsigned short*)alloc((size_t)NN * D2 * 2);
  int* gcursor = cursor + NN;        // inside the zeroed 3*NNP region, unused slot

  // --- preamble: memset + fused init/deg + scan(+atomic boff) + fill ---
  hipMemsetAsync(cnti, 0, (size_t)3 * NNP * 4, stream);
  k_initdeg<<<(IDG_TOT + 255) / 256, 256, 0, stream>>>(
      x, Wl1, Wr1, Wl2, Wr2, dst, eattr, cnti, lsum, xb, Wc1, Wc2);
  k_scan1<<<NB, 256, 0, stream>>>(cnti, lsum, rowoff, boff, gcursor, la);
  k_fill<<<(NE + 255) / 256, 256, 0, stream>>>(src, dst, eattr, rowoff, boff, cursor, se);

  const int GB = NN / 4;             // 4 nodes/block, 1 wave each (NN % 4 == 0)
  const int MB = (NN + 127) / 128;   // 235 row-tiles

  // --- layer 1: [xl1|xr1] = x @ [Wl1;Wr1]^T + [bl1;br1]  (split bf16 out) ---
  gemm_mfma<128, 4><<<dim3(2 * D1 / 128, MB), 256, 0, stream>>>(
      xb, Wc1, bl1, br1, D1, xl1, xr1, NN, 2 * D1, D2);
  k_gat_node<D1, true, true, false><<<GB, 256, 0, stream>>>(
      se, rowoff, boff, cnti, la, xl1, xr1, We1, att1, bias1, w_ln1, nullptr, h1b, nullptr);

  // --- layer 2: [xl2|xr2] = h1 @ [Wl2;Wr2]^T + [bl2;br2]  (split bf16 out) ---
  gemm_mfma<64, 2><<<dim3(2 * D2 / 64, MB), 256, 0, stream>>>(
      h1b, Wc2, bl2, br2, D2, xl2, xr2, NN, 2 * D2, D1);
  k_gat_node<D2, false, false, true><<<GB, 256, 0, stream>>>(
      se, rowoff, boff, cnti, la, xl2, xr2, We2, att2, bias2, w_ln3, W_out, nullptr, out);
}